// Round 11
// baseline (353.441 us; speedup 1.0000x reference)
//
#include <hip/hip_runtime.h>
#include <cstddef>

#define NN 1000
#define NE 8000
#define FIN 64
#define DH 128
#define RD 64
#define FEPS 1e-5f

typedef short short8 __attribute__((ext_vector_type(8)));
typedef float f32x4 __attribute__((ext_vector_type(4)));

__device__ __forceinline__ float lrelu(float x){ return x > 0.f ? x : 0.01f*x; }

__device__ __forceinline__ unsigned short f2b(float x){
  union { float f; unsigned int u; } v; v.f = x;
  unsigned int r = (v.u + 0x7fffu + ((v.u >> 16) & 1u)) >> 16;
  return (unsigned short)r;
}
__device__ __forceinline__ float b2f(unsigned int lo16){
  union { unsigned int u; float f; } v; v.u = lo16 << 16; return v.f;
}
__device__ __forceinline__ unsigned int pack2(float a, float b){
  return (unsigned int)f2b(a) | ((unsigned int)f2b(b) << 16);
}

// --- prep: block0 = topology+CSR+degree-sort; blocks 1..88 = weight prep;
//     blocks 89.. = wmean0 (one block per batch, plain store) ---

__global__ __launch_bounds__(1024) void k_prep(const int* __restrict__ src,
        const int* __restrict__ dst,
        const float* __restrict__ W1, const float* __restrict__ W2,
        const float* __restrict__ W3, const float* __restrict__ phiW,
        unsigned short* __restrict__ wt,
        const float* __restrict__ x, const float* __restrict__ gw,
        const float* __restrict__ AR, float* __restrict__ out,
        float* nout, float* nin, int* rp, int* ord,
        int* csr_s, int* csr_e, int* csr_d, int B){
  __shared__ int sdo[1024], sdi[1024], ssc[1024], sfill[1024];
  __shared__ int hist[256], hoff[256];
  __shared__ float red2[16][64];
  int bid = blockIdx.x, t = threadIdx.x;

  if (bid == 0){
    sdo[t] = 0; sdi[t] = 0;
    __syncthreads();
    for (int e = t; e < NE; e += 1024){
      atomicAdd(&sdo[src[e]], 1);
      atomicAdd(&sdi[dst[e]], 1);
    }
    __syncthreads();
    int d = sdi[t];
    ssc[t] = d; __syncthreads();
    for (int off = 1; off < 1024; off <<= 1){
      int v = (t >= off) ? ssc[t-off] : 0;
      __syncthreads();
      ssc[t] += v;
      __syncthreads();
    }
    int myrp = ssc[t] - d;
    if (t < NN){
      rp[t] = myrp;
      nin[t]  = rsqrtf((float)max(sdi[t], 1));
      nout[t] = rsqrtf((float)max(sdo[t], 1));
    }
    if (t == NN-1) rp[NN] = ssc[t];
    sfill[t] = myrp;
    __syncthreads();
    for (int e = t; e < NE; e += 1024){
      int dn = dst[e];
      int pos = atomicAdd(&sfill[dn], 1);
      csr_s[pos] = src[e];
      csr_e[pos] = e;
      csr_d[pos] = dn;
    }
    // counting sort of nodes by in-degree -> ord (perf-only permutation)
    if (t < 256) hist[t] = 0;
    __syncthreads();
    if (t < NN) atomicAdd(&hist[min(sdi[t], 255)], 1);
    __syncthreads();
    if (t < 256) hoff[t] = hist[t];
    __syncthreads();
    for (int off = 1; off < 256; off <<= 1){
      int v = (t < 256 && t >= off) ? hoff[t-off] : 0;
      __syncthreads();
      if (t < 256) hoff[t] += v;
      __syncthreads();
    }
    if (t < 256) hoff[t] -= hist[t];
    __syncthreads();
    if (t < NN){
      int pos = atomicAdd(&hoff[min(sdi[t], 255)], 1);
      ord[pos] = t;
    }
  } else if (bid <= 88){
    int i = (bid-1)*1024 + t;          // 88*1024 = 90112 exactly
    if (i < 8192){                      // W1: 64x128 -> [128][64]
      int n = i >> 6, k = i & 63;
      wt[i] = f2b(W1[k*128 + n]);
    } else if (i < 24576){              // W2 -> [128][128]
      int j = i - 8192; int n = j >> 7, k = j & 127;
      wt[i] = f2b(W2[k*128 + n]);
    } else if (i < 40960){              // W3
      int j = i - 24576; int n = j >> 7, k = j & 127;
      wt[i] = f2b(W3[k*128 + n]);
    } else {                            // phiW[3]
      int j = i - 40960; int m = j >> 14; int jj = j & 16383;
      int n = jj >> 7, k = jj & 127;
      wt[i] = f2b(phiW[m*16384 + k*128 + n]);
    }
  } else {
    int b = bid - 89;
    int r = t >> 6, l = t & 63;
    float acc = 0.f;
    for (int v = r; v < NN; v += 16)
      acc += gw[(size_t)b*NN + v]*AR[v]*x[((size_t)b*NN + v)*FIN + l];
    red2[r][l] = acc;
    __syncthreads();
    if (t < 64){
      float s = 0.f;
      #pragma unroll
      for (int g2 = 0; g2 < 16; ++g2) s += red2[g2][t];
      out[(size_t)b*640 + t] = s*(1.f/NN);
    }
  }
}

// ------- edge streams + statz zeroing -------

__global__ __launch_bounds__(256) void k_edge(const float* __restrict__ ew,
        const float* __restrict__ sup, const float* __restrict__ nout,
        const float* __restrict__ nin, const int* __restrict__ csr_s,
        const int* __restrict__ csr_e, const int* __restrict__ csr_d,
        int2* __restrict__ ecl, float* __restrict__ statz, int nz4, int B){
  int bid = blockIdx.x, t = threadIdx.x;
  int gi = bid*256 + t;
  if (gi < nz4) ((float4*)statz)[gi] = make_float4(0.f,0.f,0.f,0.f);
  int layer, b, q;
  if ((B & 7) == 0){
    int xcd = bid & 7, r = bid >> 3;
    int bsub = r/12, rem = r - bsub*12;
    layer = rem >> 2; q = rem & 3; b = bsub*8 + xcd;
  } else {
    layer = bid/(4*B);
    int rem = bid - layer*4*B;
    b = rem >> 2; q = rem & 3;
  }
  const float* ewb  = ew  + (size_t)b*NE;
  const float* supl = sup + (size_t)layer*NE;
  int2* o = ecl + ((size_t)layer*B + b)*NE;
  for (int k = q*2000 + t; k < q*2000 + 2000; k += 256){
    int e = csr_e[k]; int s = csr_s[k];
    float wv = ewb[e]*supl[e]*nout[s]*nin[csr_d[k]];
    int2 v; v.x = s; v.y = __float_as_int(wv);
    o[k] = v;
  }
}

// ------- gather layer 0: LDS-staged x quarter (16 fp32 dims), all nodes -------
// block = (batch, quarter); 512 threads = 32 groups x 16 lanes

__global__ __launch_bounds__(512) void k_gathF(const float* __restrict__ x,
        const int2* __restrict__ ec, const int* __restrict__ rp,
        const int* __restrict__ ord, unsigned short* __restrict__ agg, int B){
  __shared__ __align__(16) float sh[NN*16];   // 64000 B
  int bid = blockIdx.x;
  int b, q;
  if ((B & 7) == 0){
    int xcd = bid & 7, r = bid >> 3;
    q = r & 3; b = (r >> 2)*8 + xcd;
  } else { b = bid >> 2; q = bid & 3; }
  int t = threadIdx.x;
  const float* xb = x + (size_t)b*NN*FIN + q*16;
  for (int i = t; i < NN*4; i += 512){
    int row = i >> 2, c = i & 3;
    float4 v = *(const float4*)(xb + row*FIN + c*4);
    *(float4*)(sh + row*16 + c*4) = v;
  }
  __syncthreads();
  int grp = t >> 4, j = t & 15;
  const int2* ecb = ec + (size_t)b*NE;
  for (int rk = grp; rk < NN; rk += 32){
    int v = ord[rk];
    int kb = rp[v], ke = rp[v+1];
    float a0=0.f, a1=0.f, a2=0.f, a3=0.f;
    int k = kb;
    for (; k+3 < ke; k += 4){
      int2 e0 = ecb[k], e1 = ecb[k+1], e2 = ecb[k+2], e3 = ecb[k+3];
      a0 = fmaf(sh[e0.x*16 + j], __int_as_float(e0.y), a0);
      a1 = fmaf(sh[e1.x*16 + j], __int_as_float(e1.y), a1);
      a2 = fmaf(sh[e2.x*16 + j], __int_as_float(e2.y), a2);
      a3 = fmaf(sh[e3.x*16 + j], __int_as_float(e3.y), a3);
    }
    for (; k < ke; ++k){
      int2 e0 = ecb[k];
      a0 = fmaf(sh[e0.x*16 + j], __int_as_float(e0.y), a0);
    }
    agg[((size_t)b*NN + v)*FIN + q*16 + j] = f2b(a0+a1+a2+a3);
  }
}

// ------- gather layers 1,2: LDS-staged hnorm quarter (32 bf16 dims), all nodes -------

__global__ __launch_bounds__(512) void k_gathB(const unsigned short* __restrict__ h,
        const int2* __restrict__ ec, const int* __restrict__ rp,
        const int* __restrict__ ord, unsigned short* __restrict__ agg, int B){
  __shared__ __align__(16) unsigned shu[NN*16];   // 64000 B (1000 rows x 32 bf16)
  int bid = blockIdx.x;
  int b, q;
  if ((B & 7) == 0){
    int xcd = bid & 7, r = bid >> 3;
    q = r & 3; b = (r >> 2)*8 + xcd;
  } else { b = bid >> 2; q = bid & 3; }
  int t = threadIdx.x;
  const unsigned short* hb = h + (size_t)b*NN*DH + q*32;
  for (int i = t; i < NN*4; i += 512){
    int row = i >> 2, c = i & 3;
    uint4 v = *(const uint4*)(hb + row*DH + c*8);
    *(uint4*)(shu + row*16 + c*4) = v;
  }
  __syncthreads();
  int grp = t >> 4, j = t & 15;
  const int2* ecb = ec + (size_t)b*NE;
  for (int rk = grp; rk < NN; rk += 32){
    int v = ord[rk];
    int kb = rp[v], ke = rp[v+1];
    float a[4][2] = {};
    int k = kb;
    for (; k+3 < ke; k += 4){
      int2 e0 = ecb[k], e1 = ecb[k+1], e2 = ecb[k+2], e3 = ecb[k+3];
      unsigned u0 = shu[e0.x*16 + j], u1 = shu[e1.x*16 + j];
      unsigned u2 = shu[e2.x*16 + j], u3 = shu[e3.x*16 + j];
      float w0 = __int_as_float(e0.y), w1 = __int_as_float(e1.y);
      float w2 = __int_as_float(e2.y), w3 = __int_as_float(e3.y);
      a[0][0] = fmaf(b2f(u0 & 0xffffu), w0, a[0][0]);
      a[0][1] = fmaf(b2f(u0 >> 16),     w0, a[0][1]);
      a[1][0] = fmaf(b2f(u1 & 0xffffu), w1, a[1][0]);
      a[1][1] = fmaf(b2f(u1 >> 16),     w1, a[1][1]);
      a[2][0] = fmaf(b2f(u2 & 0xffffu), w2, a[2][0]);
      a[2][1] = fmaf(b2f(u2 >> 16),     w2, a[2][1]);
      a[3][0] = fmaf(b2f(u3 & 0xffffu), w3, a[3][0]);
      a[3][1] = fmaf(b2f(u3 >> 16),     w3, a[3][1]);
    }
    for (; k < ke; ++k){
      int2 e0 = ecb[k];
      unsigned u0 = shu[e0.x*16 + j];
      float w0 = __int_as_float(e0.y);
      a[0][0] = fmaf(b2f(u0 & 0xffffu), w0, a[0][0]);
      a[0][1] = fmaf(b2f(u0 >> 16),     w0, a[0][1]);
    }
    unsigned o = pack2(a[0][0]+a[1][0]+a[2][0]+a[3][0],
                       a[0][1]+a[1][1]+a[2][1]+a[3][1]);
    *(unsigned*)(agg + ((size_t)b*NN + v)*DH + q*32 + j*2) = o;
  }
}

// ---------------- conv MFMA GEMM + fused stats (ssum/ssq atomics) ----------------

template<int K>
__global__ __launch_bounds__(256) void k_conv(const unsigned short* __restrict__ A,
        const unsigned short* __restrict__ Wt, unsigned short* __restrict__ Cb,
        float* __restrict__ red_out, int B){
  constexpr int K2 = K*2;
  constexpr int CPR = K/8;
  __shared__ __align__(16) char smem[64*K2 + 128*K2];
  char* sA = smem;
  char* sW = smem + 64*K2;
  int t = threadIdx.x;
  int b, tile;
  if ((B & 7) == 0){
    int xcd = blockIdx.x & 7, r = blockIdx.x >> 3;
    int bsub = r >> 4; tile = r & 15; b = bsub*8 + xcd;
  } else { b = blockIdx.x >> 4; tile = blockIdx.x & 15; }
  int rows = NN - tile*64; if (rows > 64) rows = 64;
  size_t row0 = (size_t)b*NN + tile*64;
  size_t Mtot = (size_t)B*NN;

  for (int i = t; i < 64*CPR; i += 256){
    int r = i/CPR, cb = i%CPR;
    size_t gr = row0 + r; if (gr >= Mtot) gr = Mtot - 1;
    uint4 v = *(const uint4*)(A + gr*K + cb*8);
    *(uint4*)(sA + r*K2 + ((cb*16) ^ ((r & 7) << 4))) = v;
  }
  for (int i = t; i < 128*CPR; i += 256){
    int n = i/CPR, cb = i%CPR;
    uint4 v = *(const uint4*)(Wt + n*K + cb*8);
    *(uint4*)(sW + n*K2 + ((cb*16) ^ ((n & 7) << 4))) = v;
  }
  __syncthreads();

  int w = t >> 6, l = t & 63;
  int lr = l & 15, lk = l >> 4;
  f32x4 acc[8] = {};
  int arow = w*16 + lr;
  #pragma unroll
  for (int kk = 0; kk < K/32; ++kk){
    int kb = kk*64 + lk*16;
    short8 a = *(const short8*)(sA + arow*K2 + (kb ^ ((arow & 7) << 4)));
    #pragma unroll
    for (int f = 0; f < 8; ++f){
      int n = f*16 + lr;
      short8 bf = *(const short8*)(sW + n*K2 + (kb ^ ((n & 7) << 4)));
      acc[f] = __builtin_amdgcn_mfma_f32_16x16x32_bf16(a, bf, acc[f], 0, 0, 0);
    }
  }
  __syncthreads();

  float* red = (float*)smem;
  float cs[8], cq[8];
  int rbase = w*16 + lk*4;
  #pragma unroll
  for (int f = 0; f < 8; ++f){
    int col = f*16 + lr;
    float s = 0.f, q = 0.f;
    #pragma unroll
    for (int r = 0; r < 4; ++r){
      int row = rbase + r;
      bool ok = row < rows;
      float v = acc[f][r];
      if (ok) Cb[(row0 + row)*DH + col] = f2b(v);
      s += ok ? v : 0.f;
      q += ok ? v*v : 0.f;
    }
    s += __shfl_xor(s, 16); s += __shfl_xor(s, 32);
    q += __shfl_xor(q, 16); q += __shfl_xor(q, 32);
    cs[f] = s; cq[f] = q;
  }
  if (l < 16){
    #pragma unroll
    for (int f = 0; f < 8; ++f){
      red[w*128 + f*16 + l] = cs[f];
      red[512 + w*128 + f*16 + l] = cq[f];
    }
  }
  __syncthreads();
  if (t < 128){
    float s = red[t] + red[128+t] + red[256+t] + red[384+t];
    atomicAdd(&red_out[(size_t)b*DH + t], s);
    float q = red[512+t] + red[640+t] + red[768+t] + red[896+t];
    atomicAdd(&red_out[(size_t)B*DH + (size_t)b*DH + t], q);
  }
}

// -- phi MFMA: inline finstats + norm-in-staging (+optional hnorm), z-reduce + wmean --

__global__ __launch_bounds__(256) void k_phi(const unsigned short* __restrict__ hpre,
        const unsigned short* __restrict__ Wt,
        const float* __restrict__ ssum, const float* __restrict__ ssq,
        const float* __restrict__ alpha, const float* __restrict__ gamma,
        const float* __restrict__ beta, const float* __restrict__ bias,
        const float* __restrict__ gw, const float* __restrict__ ar,
        unsigned short* __restrict__ hnorm,
        float* __restrict__ zout, float* __restrict__ out, int off, int B){
  __shared__ __align__(16) char smem[64*256 + 128*256];
  __shared__ __align__(16) float sivg[128], spc[128];
  __shared__ float sgw[64];
  char* sA = smem;
  char* sW = smem + 64*256;
  int t = threadIdx.x;
  int b, tile;
  if ((B & 7) == 0){
    int xcd = blockIdx.x & 7, r = blockIdx.x >> 3;
    int bsub = r >> 4; tile = r & 15; b = bsub*8 + xcd;
  } else { b = blockIdx.x >> 4; tile = blockIdx.x & 15; }
  int rows = NN - tile*64; if (rows > 64) rows = 64;
  size_t row0 = (size_t)b*NN + tile*64;

  if (t < 128){
    float m   = ssum[(size_t)b*DH + t]*(1.f/NN);
    float ex2 = ssq [(size_t)b*DH + t]*(1.f/NN);
    float a = alpha[t];
    float var = ex2 - (2.f*a - a*a)*m*m;
    float g = gamma[t]*rsqrtf(var + FEPS);
    sivg[t] = g;
    spc [t] = beta[t] - a*m*g;
  } else if (t < 192){
    int vr = tile*64 + (t - 128);
    sgw[t-128] = (vr < NN) ? gw[(size_t)b*NN + vr]*ar[vr] : 0.f;
  }
  __syncthreads();

  for (int i = t; i < 64*16; i += 256){
    int r = i >> 4, cb = i & 15;
    int rr = (r < rows) ? r : 0;
    uint4 u = *(const uint4*)(hpre + (row0 + rr)*DH + cb*8);
    int c0 = cb*8;
    float4 g1 = *(const float4*)(sivg + c0), g2 = *(const float4*)(sivg + c0 + 4);
    float4 p1 = *(const float4*)(spc + c0),  p2 = *(const float4*)(spc + c0 + 4);
    float xv[8];
    xv[0] = b2f(u.x & 0xffffu); xv[1] = b2f(u.x >> 16);
    xv[2] = b2f(u.y & 0xffffu); xv[3] = b2f(u.y >> 16);
    xv[4] = b2f(u.z & 0xffffu); xv[5] = b2f(u.z >> 16);
    xv[6] = b2f(u.w & 0xffffu); xv[7] = b2f(u.w >> 16);
    float gg[8] = {g1.x,g1.y,g1.z,g1.w,g2.x,g2.y,g2.z,g2.w};
    float pv[8] = {p1.x,p1.y,p1.z,p1.w,p2.x,p2.y,p2.z,p2.w};
    float nv[8];
    #pragma unroll
    for (int d2 = 0; d2 < 8; ++d2){
      float n0 = fmaf(xv[d2], gg[d2], pv[d2]);
      nv[d2] = fmaxf(n0, 0.01f*n0);
    }
    uint4 o;
    o.x = pack2(nv[0],nv[1]); o.y = pack2(nv[2],nv[3]);
    o.z = pack2(nv[4],nv[5]); o.w = pack2(nv[6],nv[7]);
    *(uint4*)(sA + r*256 + ((cb*16) ^ ((r & 7) << 4))) = o;
    if (hnorm != nullptr && r < rows)
      *(uint4*)(hnorm + (row0 + r)*DH + cb*8) = o;
  }
  for (int i = t; i < 128*16; i += 256){
    int n = i >> 4, cb = i & 15;
    uint4 v = *(const uint4*)(Wt + n*DH + cb*8);
    *(uint4*)(sW + n*256 + ((cb*16) ^ ((n & 7) << 4))) = v;
  }
  __syncthreads();

  int w = t >> 6, l = t & 63;
  int lr = l & 15, lk = l >> 4;
  f32x4 acc[8] = {};
  int arow = w*16 + lr;
  #pragma unroll
  for (int kk = 0; kk < 4; ++kk){
    int kb = kk*64 + lk*16;
    short8 a = *(const short8*)(sA + arow*256 + (kb ^ ((arow & 7) << 4)));
    #pragma unroll
    for (int f = 0; f < 8; ++f){
      int n = f*16 + lr;
      short8 bf = *(const short8*)(sW + n*256 + (kb ^ ((n & 7) << 4)));
      acc[f] = __builtin_amdgcn_mfma_f32_16x16x32_bf16(a, bf, acc[f], 0, 0, 0);
    }
  }
  __syncthreads();

  float* red = (float*)sW;
  float cs[8];
  int rbase = w*16 + lk*4;
  #pragma unroll
  for (int f = 0; f < 8; ++f){
    int col = f*16 + lr;
    float bv = bias[col];
    float s = 0.f;
    #pragma unroll
    for (int r = 0; r < 4; ++r){
      int row = rbase + r;
      float u = lrelu(acc[f][r] + bv);
      s += (row < rows) ? u : 0.f;
    }
    s += __shfl_xor(s, 16); s += __shfl_xor(s, 32);
    cs[f] = s;
  }
  if (l < 16){
    #pragma unroll
    for (int f = 0; f < 8; ++f) red[w*128 + f*16 + l] = cs[f];
  }
  __syncthreads();
  if (t < 128){
    float s = red[t] + red[128+t] + red[256+t] + red[384+t];
    atomicAdd(&zout[(size_t)b*DH + t], s);
  } else {
    int col = t - 128;
    float s = 0.f;
    for (int r = 0; r < 64; ++r){
      int byteoff = r*256 + (((col >> 3)*16) ^ ((r & 7) << 4)) + (col & 7)*2;
      s += sgw[r]*b2f(*(const unsigned short*)(sA + byteoff));
    }
    atomicAdd(&out[(size_t)b*640 + off + col], s*(1.f/NN));
  }
}

// ------- final: rho (3 layers) + output lrelu, one block per batch -------

__global__ void k_final(const float* __restrict__ statz, const float* __restrict__ rhoW,
                        const float* __restrict__ rhob, float* __restrict__ out, int B){
  int b = blockIdx.x;
  int t = threadIdx.x; // 256
  if (t < 192){
    int i = t >> 6, d = t & 63;
    const float* z = statz + ((size_t)i*3 + 2)*(size_t)B*DH + (size_t)b*DH;
    float acc = rhob[i*RD + d];
    const float* Wm = rhoW + (size_t)i*DH*RD;
    for (int k = 0; k < DH; ++k) acc = fmaf(z[k], Wm[k*RD + d], acc);
    out[(size_t)b*640 + 64 + i*192 + d] = lrelu(lrelu(acc));
  }
  // lrelu the wmean sections: [0,64) U [128,256) U [320,448) U [512,640)
  for (int s = t; s < 448; s += 256){
    int idx;
    if (s < 64) idx = s;
    else { int j = s - 64; idx = 128 + (j >> 7)*192 + (j & 127); }
    size_t gi = (size_t)b*640 + idx;
    out[gi] = lrelu(out[gi]);
  }
}

// ---------------- launcher ----------------

extern "C" void kernel_launch(void* const* d_in, const int* in_sizes, int n_in,
                              void* d_out, int out_size, void* d_ws, size_t ws_size,
                              hipStream_t stream){
  const float* x    = (const float*)d_in[0];
  const float* ew   = (const float*)d_in[1];
  const float* gw   = (const float*)d_in[2];
  const float* W1   = (const float*)d_in[3];
  const float* W2   = (const float*)d_in[4];
  const float* W3   = (const float*)d_in[5];
  const float* sup  = (const float*)d_in[6];
  const float* AR   = (const float*)d_in[7];
  const float* gam  = (const float*)d_in[8];
  const float* bet  = (const float*)d_in[9];
  const float* alp  = (const float*)d_in[10];
  const float* phiW = (const float*)d_in[11];
  const float* phib = (const float*)d_in[12];
  const float* rhoW = (const float*)d_in[13];
  const float* rhob = (const float*)d_in[14];
  const int*   src  = (const int*)d_in[15];
  const int*   dst  = (const int*)d_in[16];
  float* out = (float*)d_out;

  int B = in_sizes[0] / (NN*FIN);
  size_t M = (size_t)B*NN;
  size_t BD = (size_t)B*DH;

  float* w = (float*)d_ws;
  size_t p = 0;
  float* nout = w+p; p += 1024;
  float* nin  = w+p; p += 1024;
  int* rp     = (int*)(w+p); p += 1024;
  int* ord    = (int*)(w+p); p += 1024;
  int* csr_s  = (int*)(w+p); p += 8192;
  int* csr_e  = (int*)(w+p); p += 8192;
  int* csr_d  = (int*)(w+p); p += 8192;
  float* statz = w+p; p += 3*3*BD;           // per layer: [ssum | ssq | zbuf]
  unsigned short* wt = (unsigned short*)(w+p); p += 45056;   // 90112 bf16
  int2* ecl   = (int2*)(w+p); p += (size_t)6*B*NE;
  unsigned short* hpre  = (unsigned short*)(w+p); p += M*DH/2;
  unsigned short* hnorm = (unsigned short*)(w+p); p += M*DH/2;
  unsigned short* agg   = (unsigned short*)(w+p); p += M*DH/2;

  hipMemsetAsync(out, 0, (size_t)out_size*sizeof(float), stream);

  k_prep<<<89 + B, 1024, 0, stream>>>(src, dst, W1, W2, W3, phiW, wt,
      x, gw, AR, out, nout, nin, rp, ord, csr_s, csr_e, csr_d, B);
  k_edge<<<12*B, 256, 0, stream>>>(ew, sup, nout, nin, csr_s, csr_e, csr_d,
      ecl, statz, (int)(9*BD/4), B);

  const int wt_off[3] = {0, 8192, 24576};

  for (int i = 0; i < 3; ++i){
    float* SS = statz + (size_t)i*3*BD;
    if (i == 0){
      k_gathF<<<4*B, 512, 0, stream>>>(x, ecl, rp, ord, agg, B);
      k_conv<FIN><<<B*16, 256, 0, stream>>>(agg, wt, hpre, SS, B);
    } else {
      k_gathB<<<4*B, 512, 0, stream>>>(hnorm, ecl + (size_t)i*B*NE, rp, ord, agg, B);
      k_conv<DH><<<B*16, 256, 0, stream>>>(agg, wt + wt_off[i], hpre, SS, B);
    }
    k_phi<<<B*16, 256, 0, stream>>>(hpre, wt + 40960 + i*16384,
        SS, SS + BD, alp + i*DH, gam + i*DH, bet + i*DH, phib + i*DH,
        gw, AR + (size_t)(i+1)*NN, (i == 2) ? nullptr : hnorm,
        SS + 2*BD, out, 128 + i*192, B);
  }

  k_final<<<B, 256, 0, stream>>>(statz, rhoW, rhob, out, B);
}

// Round 12
// 268.364 us; speedup vs baseline: 1.3170x; 1.3170x over previous
//
#include <hip/hip_runtime.h>
#include <cstddef>

#define NN 1000
#define NE 8000
#define FIN 64
#define DH 128
#define RD 64
#define FEPS 1e-5f

typedef short short8 __attribute__((ext_vector_type(8)));
typedef float f32x4 __attribute__((ext_vector_type(4)));

__device__ __forceinline__ float lrelu(float x){ return x > 0.f ? x : 0.01f*x; }

__device__ __forceinline__ unsigned short f2b(float x){
  union { float f; unsigned int u; } v; v.f = x;
  unsigned int r = (v.u + 0x7fffu + ((v.u >> 16) & 1u)) >> 16;
  return (unsigned short)r;
}
__device__ __forceinline__ float b2f(unsigned int lo16){
  union { unsigned int u; float f; } v; v.u = lo16 << 16; return v.f;
}
__device__ __forceinline__ unsigned int pack2(float a, float b){
  return (unsigned int)f2b(a) | ((unsigned int)f2b(b) << 16);
}

// --- prep: block0 = topology+CSR+degree-sort; blocks 1..88 = weight prep;
//     blocks 89.. = wmean0 (one block per batch, plain store) ---

__global__ __launch_bounds__(1024) void k_prep(const int* __restrict__ src,
        const int* __restrict__ dst,
        const float* __restrict__ W1, const float* __restrict__ W2,
        const float* __restrict__ W3, const float* __restrict__ phiW,
        unsigned short* __restrict__ wt,
        const float* __restrict__ x, const float* __restrict__ gw,
        const float* __restrict__ AR, float* __restrict__ out,
        float* nout, float* nin, int* rp, int* ord,
        int* csr_s, int* csr_e, int* csr_d, int B){
  __shared__ int sdo[1024], sdi[1024], ssc[1024], sfill[1024];
  __shared__ int hist[256], hoff[256];
  __shared__ float red2[16][64];
  int bid = blockIdx.x, t = threadIdx.x;

  if (bid == 0){
    sdo[t] = 0; sdi[t] = 0;
    __syncthreads();
    for (int e = t; e < NE; e += 1024){
      atomicAdd(&sdo[src[e]], 1);
      atomicAdd(&sdi[dst[e]], 1);
    }
    __syncthreads();
    int d = sdi[t];
    ssc[t] = d; __syncthreads();
    for (int off = 1; off < 1024; off <<= 1){
      int v = (t >= off) ? ssc[t-off] : 0;
      __syncthreads();
      ssc[t] += v;
      __syncthreads();
    }
    int myrp = ssc[t] - d;
    if (t < NN){
      rp[t] = myrp;
      nin[t]  = rsqrtf((float)max(sdi[t], 1));
      nout[t] = rsqrtf((float)max(sdo[t], 1));
    }
    if (t == NN-1) rp[NN] = ssc[t];
    sfill[t] = myrp;
    __syncthreads();
    for (int e = t; e < NE; e += 1024){
      int dn = dst[e];
      int pos = atomicAdd(&sfill[dn], 1);
      csr_s[pos] = src[e];
      csr_e[pos] = e;
      csr_d[pos] = dn;
    }
    // counting sort of nodes by in-degree -> ord (perf-only permutation)
    if (t < 256) hist[t] = 0;
    __syncthreads();
    if (t < NN) atomicAdd(&hist[min(sdi[t], 255)], 1);
    __syncthreads();
    if (t < 256) hoff[t] = hist[t];
    __syncthreads();
    for (int off = 1; off < 256; off <<= 1){
      int v = (t < 256 && t >= off) ? hoff[t-off] : 0;
      __syncthreads();
      if (t < 256) hoff[t] += v;
      __syncthreads();
    }
    if (t < 256) hoff[t] -= hist[t];
    __syncthreads();
    if (t < NN){
      int pos = atomicAdd(&hoff[min(sdi[t], 255)], 1);
      ord[pos] = t;
    }
  } else if (bid <= 88){
    int i = (bid-1)*1024 + t;          // 88*1024 = 90112 exactly
    if (i < 8192){                      // W1: 64x128 -> [128][64]
      int n = i >> 6, k = i & 63;
      wt[i] = f2b(W1[k*128 + n]);
    } else if (i < 24576){              // W2 -> [128][128]
      int j = i - 8192; int n = j >> 7, k = j & 127;
      wt[i] = f2b(W2[k*128 + n]);
    } else if (i < 40960){              // W3
      int j = i - 24576; int n = j >> 7, k = j & 127;
      wt[i] = f2b(W3[k*128 + n]);
    } else {                            // phiW[3]
      int j = i - 40960; int m = j >> 14; int jj = j & 16383;
      int n = jj >> 7, k = jj & 127;
      wt[i] = f2b(phiW[m*16384 + k*128 + n]);
    }
  } else {
    int b = bid - 89;
    int r = t >> 6, l = t & 63;
    float acc = 0.f;
    for (int v = r; v < NN; v += 16)
      acc += gw[(size_t)b*NN + v]*AR[v]*x[((size_t)b*NN + v)*FIN + l];
    red2[r][l] = acc;
    __syncthreads();
    if (t < 64){
      float s = 0.f;
      #pragma unroll
      for (int g2 = 0; g2 < 16; ++g2) s += red2[g2][t];
      out[(size_t)b*640 + t] = s*(1.f/NN);
    }
  }
}

// ------- edge streams + statz zeroing -------

__global__ __launch_bounds__(256) void k_edge(const float* __restrict__ ew,
        const float* __restrict__ sup, const float* __restrict__ nout,
        const float* __restrict__ nin, const int* __restrict__ csr_s,
        const int* __restrict__ csr_e, const int* __restrict__ csr_d,
        int2* __restrict__ ecl, float* __restrict__ statz, int nz4, int B){
  int bid = blockIdx.x, t = threadIdx.x;
  int gi = bid*256 + t;
  if (gi < nz4) ((float4*)statz)[gi] = make_float4(0.f,0.f,0.f,0.f);
  int layer, b, q;
  if ((B & 7) == 0){
    int xcd = bid & 7, r = bid >> 3;
    int bsub = r/12, rem = r - bsub*12;
    layer = rem >> 2; q = rem & 3; b = bsub*8 + xcd;
  } else {
    layer = bid/(4*B);
    int rem = bid - layer*4*B;
    b = rem >> 2; q = rem & 3;
  }
  const float* ewb  = ew  + (size_t)b*NE;
  const float* supl = sup + (size_t)layer*NE;
  int2* o = ecl + ((size_t)layer*B + b)*NE;
  for (int k = q*2000 + t; k < q*2000 + 2000; k += 256){
    int e = csr_e[k]; int s = csr_s[k];
    float wv = ewb[e]*supl[e]*nout[s]*nin[csr_d[k]];
    int2 v; v.x = s; v.y = __float_as_int(wv);
    o[k] = v;
  }
}

// ------- gather layer 0: x fp32, degree-sorted nodes, 4-way unroll -------

__global__ __launch_bounds__(256) void k_gathF(const float* __restrict__ x,
        const int2* __restrict__ ec, const int* __restrict__ rp,
        const int* __restrict__ ord, unsigned short* __restrict__ agg, int B){
  int bid = blockIdx.x;
  int b, chunk;
  if ((B & 7) == 0){
    int xcd = bid & 7, r = bid >> 3;
    int bsub = r/63; chunk = r - bsub*63; b = bsub*8 + xcd;
  } else { b = bid/63; chunk = bid - b*63; }
  int t = threadIdx.x;
  int grp = t >> 4, j = t & 15;
  int rk = chunk*16 + grp; if (rk > NN-1) rk = NN-1;
  int v = ord[rk];
  int kb = rp[v], ke = rp[v+1];
  const float* xb = x + (size_t)b*NN*FIN;
  const int2* ecb = ec + (size_t)b*NE;
  float acc[4][4] = {};
  int k = kb;
  for (; k+3 < ke; k += 4){
    #pragma unroll
    for (int uu = 0; uu < 4; ++uu){
      int2 e = ecb[k+uu];
      float4 xr = *(const float4*)(xb + e.x*FIN + j*4);
      float wgt = __int_as_float(e.y);
      acc[uu][0] = fmaf(xr.x, wgt, acc[uu][0]);
      acc[uu][1] = fmaf(xr.y, wgt, acc[uu][1]);
      acc[uu][2] = fmaf(xr.z, wgt, acc[uu][2]);
      acc[uu][3] = fmaf(xr.w, wgt, acc[uu][3]);
    }
  }
  for (; k < ke; ++k){
    int2 e = ecb[k];
    float4 xr = *(const float4*)(xb + e.x*FIN + j*4);
    float wgt = __int_as_float(e.y);
    acc[0][0] = fmaf(xr.x, wgt, acc[0][0]);
    acc[0][1] = fmaf(xr.y, wgt, acc[0][1]);
    acc[0][2] = fmaf(xr.z, wgt, acc[0][2]);
    acc[0][3] = fmaf(xr.w, wgt, acc[0][3]);
  }
  uint2 o;
  o.x = pack2(acc[0][0]+acc[1][0]+acc[2][0]+acc[3][0],
              acc[0][1]+acc[1][1]+acc[2][1]+acc[3][1]);
  o.y = pack2(acc[0][2]+acc[1][2]+acc[2][2]+acc[3][2],
              acc[0][3]+acc[1][3]+acc[2][3]+acc[3][3]);
  *(uint2*)(agg + ((size_t)b*NN + v)*FIN + j*4) = o;
}

// ------- gather layers 1,2: hnorm bf16, degree-sorted, 4-way unroll -------

__global__ __launch_bounds__(256) void k_gathB(const unsigned short* __restrict__ h,
        const int2* __restrict__ ec, const int* __restrict__ rp,
        const int* __restrict__ ord, unsigned short* __restrict__ agg, int B){
  int bid = blockIdx.x;
  int b, chunk;
  if ((B & 7) == 0){
    int xcd = bid & 7, r = bid >> 3;
    int bsub = r/63; chunk = r - bsub*63; b = bsub*8 + xcd;
  } else { b = bid/63; chunk = bid - b*63; }
  int t = threadIdx.x;
  int grp = t >> 4, j = t & 15;
  int rk = chunk*16 + grp; if (rk > NN-1) rk = NN-1;
  int v = ord[rk];
  int kb = rp[v], ke = rp[v+1];
  const unsigned short* hb = h + (size_t)b*NN*DH;
  const int2* ecb = ec + (size_t)b*NE;
  float acc[4][8] = {};
  int k = kb;
  for (; k+3 < ke; k += 4){
    #pragma unroll
    for (int uu = 0; uu < 4; ++uu){
      int2 e = ecb[k+uu];
      uint4 u = *(const uint4*)(hb + e.x*DH + j*8);
      float wgt = __int_as_float(e.y);
      acc[uu][0] = fmaf(b2f(u.x & 0xffffu), wgt, acc[uu][0]);
      acc[uu][1] = fmaf(b2f(u.x >> 16),     wgt, acc[uu][1]);
      acc[uu][2] = fmaf(b2f(u.y & 0xffffu), wgt, acc[uu][2]);
      acc[uu][3] = fmaf(b2f(u.y >> 16),     wgt, acc[uu][3]);
      acc[uu][4] = fmaf(b2f(u.z & 0xffffu), wgt, acc[uu][4]);
      acc[uu][5] = fmaf(b2f(u.z >> 16),     wgt, acc[uu][5]);
      acc[uu][6] = fmaf(b2f(u.w & 0xffffu), wgt, acc[uu][6]);
      acc[uu][7] = fmaf(b2f(u.w >> 16),     wgt, acc[uu][7]);
    }
  }
  for (; k < ke; ++k){
    int2 e = ecb[k];
    uint4 u = *(const uint4*)(hb + e.x*DH + j*8);
    float wgt = __int_as_float(e.y);
    acc[0][0] = fmaf(b2f(u.x & 0xffffu), wgt, acc[0][0]);
    acc[0][1] = fmaf(b2f(u.x >> 16),     wgt, acc[0][1]);
    acc[0][2] = fmaf(b2f(u.y & 0xffffu), wgt, acc[0][2]);
    acc[0][3] = fmaf(b2f(u.y >> 16),     wgt, acc[0][3]);
    acc[0][4] = fmaf(b2f(u.z & 0xffffu), wgt, acc[0][4]);
    acc[0][5] = fmaf(b2f(u.z >> 16),     wgt, acc[0][5]);
    acc[0][6] = fmaf(b2f(u.w & 0xffffu), wgt, acc[0][6]);
    acc[0][7] = fmaf(b2f(u.w >> 16),     wgt, acc[0][7]);
  }
  float f[8];
  #pragma unroll
  for (int d2 = 0; d2 < 8; ++d2)
    f[d2] = acc[0][d2]+acc[1][d2]+acc[2][d2]+acc[3][d2];
  uint4 o;
  o.x = pack2(f[0],f[1]); o.y = pack2(f[2],f[3]);
  o.z = pack2(f[4],f[5]); o.w = pack2(f[6],f[7]);
  *(uint4*)(agg + ((size_t)b*NN + v)*DH + j*8) = o;
}

// ---------------- conv MFMA GEMM + fused stats (ssum/ssq atomics) ----------------

template<int K>
__global__ __launch_bounds__(256) void k_conv(const unsigned short* __restrict__ A,
        const unsigned short* __restrict__ Wt, unsigned short* __restrict__ Cb,
        float* __restrict__ red_out, int B){
  constexpr int K2 = K*2;
  constexpr int CPR = K/8;
  __shared__ __align__(16) char smem[64*K2 + 128*K2];
  char* sA = smem;
  char* sW = smem + 64*K2;
  int t = threadIdx.x;
  int b, tile;
  if ((B & 7) == 0){
    int xcd = blockIdx.x & 7, r = blockIdx.x >> 3;
    int bsub = r >> 4; tile = r & 15; b = bsub*8 + xcd;
  } else { b = blockIdx.x >> 4; tile = blockIdx.x & 15; }
  int rows = NN - tile*64; if (rows > 64) rows = 64;
  size_t row0 = (size_t)b*NN + tile*64;
  size_t Mtot = (size_t)B*NN;

  for (int i = t; i < 64*CPR; i += 256){
    int r = i/CPR, cb = i%CPR;
    size_t gr = row0 + r; if (gr >= Mtot) gr = Mtot - 1;
    uint4 v = *(const uint4*)(A + gr*K + cb*8);
    *(uint4*)(sA + r*K2 + ((cb*16) ^ ((r & 7) << 4))) = v;
  }
  for (int i = t; i < 128*CPR; i += 256){
    int n = i/CPR, cb = i%CPR;
    uint4 v = *(const uint4*)(Wt + n*K + cb*8);
    *(uint4*)(sW + n*K2 + ((cb*16) ^ ((n & 7) << 4))) = v;
  }
  __syncthreads();

  int w = t >> 6, l = t & 63;
  int lr = l & 15, lk = l >> 4;
  f32x4 acc[8] = {};
  int arow = w*16 + lr;
  #pragma unroll
  for (int kk = 0; kk < K/32; ++kk){
    int kb = kk*64 + lk*16;
    short8 a = *(const short8*)(sA + arow*K2 + (kb ^ ((arow & 7) << 4)));
    #pragma unroll
    for (int f = 0; f < 8; ++f){
      int n = f*16 + lr;
      short8 bf = *(const short8*)(sW + n*K2 + (kb ^ ((n & 7) << 4)));
      acc[f] = __builtin_amdgcn_mfma_f32_16x16x32_bf16(a, bf, acc[f], 0, 0, 0);
    }
  }
  __syncthreads();

  float* red = (float*)smem;
  float cs[8], cq[8];
  int rbase = w*16 + lk*4;
  #pragma unroll
  for (int f = 0; f < 8; ++f){
    int col = f*16 + lr;
    float s = 0.f, q = 0.f;
    #pragma unroll
    for (int r = 0; r < 4; ++r){
      int row = rbase + r;
      bool ok = row < rows;
      float v = acc[f][r];
      if (ok) Cb[(row0 + row)*DH + col] = f2b(v);
      s += ok ? v : 0.f;
      q += ok ? v*v : 0.f;
    }
    s += __shfl_xor(s, 16); s += __shfl_xor(s, 32);
    q += __shfl_xor(q, 16); q += __shfl_xor(q, 32);
    cs[f] = s; cq[f] = q;
  }
  if (l < 16){
    #pragma unroll
    for (int f = 0; f < 8; ++f){
      red[w*128 + f*16 + l] = cs[f];
      red[512 + w*128 + f*16 + l] = cq[f];
    }
  }
  __syncthreads();
  if (t < 128){
    float s = red[t] + red[128+t] + red[256+t] + red[384+t];
    atomicAdd(&red_out[(size_t)b*DH + t], s);
    float q = red[512+t] + red[640+t] + red[768+t] + red[896+t];
    atomicAdd(&red_out[(size_t)B*DH + (size_t)b*DH + t], q);
  }
}

// -- phi MFMA: inline finstats + norm-in-staging (+optional hnorm), z-reduce + wmean --

__global__ __launch_bounds__(256) void k_phi(const unsigned short* __restrict__ hpre,
        const unsigned short* __restrict__ Wt,
        const float* __restrict__ ssum, const float* __restrict__ ssq,
        const float* __restrict__ alpha, const float* __restrict__ gamma,
        const float* __restrict__ beta, const float* __restrict__ bias,
        const float* __restrict__ gw, const float* __restrict__ ar,
        unsigned short* __restrict__ hnorm,
        float* __restrict__ zout, float* __restrict__ out, int off, int B){
  __shared__ __align__(16) char smem[64*256 + 128*256];
  __shared__ __align__(16) float sivg[128], spc[128];
  __shared__ float sgw[64];
  char* sA = smem;
  char* sW = smem + 64*256;
  int t = threadIdx.x;
  int b, tile;
  if ((B & 7) == 0){
    int xcd = blockIdx.x & 7, r = blockIdx.x >> 3;
    int bsub = r >> 4; tile = r & 15; b = bsub*8 + xcd;
  } else { b = blockIdx.x >> 4; tile = blockIdx.x & 15; }
  int rows = NN - tile*64; if (rows > 64) rows = 64;
  size_t row0 = (size_t)b*NN + tile*64;

  if (t < 128){
    float m   = ssum[(size_t)b*DH + t]*(1.f/NN);
    float ex2 = ssq [(size_t)b*DH + t]*(1.f/NN);
    float a = alpha[t];
    float var = ex2 - (2.f*a - a*a)*m*m;
    float g = gamma[t]*rsqrtf(var + FEPS);
    sivg[t] = g;
    spc [t] = beta[t] - a*m*g;
  } else if (t < 192){
    int vr = tile*64 + (t - 128);
    sgw[t-128] = (vr < NN) ? gw[(size_t)b*NN + vr]*ar[vr] : 0.f;
  }
  __syncthreads();

  for (int i = t; i < 64*16; i += 256){
    int r = i >> 4, cb = i & 15;
    int rr = (r < rows) ? r : 0;
    uint4 u = *(const uint4*)(hpre + (row0 + rr)*DH + cb*8);
    int c0 = cb*8;
    float4 g1 = *(const float4*)(sivg + c0), g2 = *(const float4*)(sivg + c0 + 4);
    float4 p1 = *(const float4*)(spc + c0),  p2 = *(const float4*)(spc + c0 + 4);
    float xv[8];
    xv[0] = b2f(u.x & 0xffffu); xv[1] = b2f(u.x >> 16);
    xv[2] = b2f(u.y & 0xffffu); xv[3] = b2f(u.y >> 16);
    xv[4] = b2f(u.z & 0xffffu); xv[5] = b2f(u.z >> 16);
    xv[6] = b2f(u.w & 0xffffu); xv[7] = b2f(u.w >> 16);
    float gg[8] = {g1.x,g1.y,g1.z,g1.w,g2.x,g2.y,g2.z,g2.w};
    float pv[8] = {p1.x,p1.y,p1.z,p1.w,p2.x,p2.y,p2.z,p2.w};
    float nv[8];
    #pragma unroll
    for (int d2 = 0; d2 < 8; ++d2){
      float n0 = fmaf(xv[d2], gg[d2], pv[d2]);
      nv[d2] = fmaxf(n0, 0.01f*n0);
    }
    uint4 o;
    o.x = pack2(nv[0],nv[1]); o.y = pack2(nv[2],nv[3]);
    o.z = pack2(nv[4],nv[5]); o.w = pack2(nv[6],nv[7]);
    *(uint4*)(sA + r*256 + ((cb*16) ^ ((r & 7) << 4))) = o;
    if (hnorm != nullptr && r < rows)
      *(uint4*)(hnorm + (row0 + r)*DH + cb*8) = o;
  }
  for (int i = t; i < 128*16; i += 256){
    int n = i >> 4, cb = i & 15;
    uint4 v = *(const uint4*)(Wt + n*DH + cb*8);
    *(uint4*)(sW + n*256 + ((cb*16) ^ ((n & 7) << 4))) = v;
  }
  __syncthreads();

  int w = t >> 6, l = t & 63;
  int lr = l & 15, lk = l >> 4;
  f32x4 acc[8] = {};
  int arow = w*16 + lr;
  #pragma unroll
  for (int kk = 0; kk < 4; ++kk){
    int kb = kk*64 + lk*16;
    short8 a = *(const short8*)(sA + arow*256 + (kb ^ ((arow & 7) << 4)));
    #pragma unroll
    for (int f = 0; f < 8; ++f){
      int n = f*16 + lr;
      short8 bf = *(const short8*)(sW + n*256 + (kb ^ ((n & 7) << 4)));
      acc[f] = __builtin_amdgcn_mfma_f32_16x16x32_bf16(a, bf, acc[f], 0, 0, 0);
    }
  }
  __syncthreads();

  float* red = (float*)sW;
  float cs[8];
  int rbase = w*16 + lk*4;
  #pragma unroll
  for (int f = 0; f < 8; ++f){
    int col = f*16 + lr;
    float bv = bias[col];
    float s = 0.f;
    #pragma unroll
    for (int r = 0; r < 4; ++r){
      int row = rbase + r;
      float u = lrelu(acc[f][r] + bv);
      s += (row < rows) ? u : 0.f;
    }
    s += __shfl_xor(s, 16); s += __shfl_xor(s, 32);
    cs[f] = s;
  }
  if (l < 16){
    #pragma unroll
    for (int f = 0; f < 8; ++f) red[w*128 + f*16 + l] = cs[f];
  }
  __syncthreads();
  if (t < 128){
    float s = red[t] + red[128+t] + red[256+t] + red[384+t];
    atomicAdd(&zout[(size_t)b*DH + t], s);
  } else {
    int col = t - 128;
    float s = 0.f;
    for (int r = 0; r < 64; ++r){
      int byteoff = r*256 + (((col >> 3)*16) ^ ((r & 7) << 4)) + (col & 7)*2;
      s += sgw[r]*b2f(*(const unsigned short*)(sA + byteoff));
    }
    atomicAdd(&out[(size_t)b*640 + off + col], s*(1.f/NN));
  }
}

// ------- final: rho (3 layers) + output lrelu, one block per batch -------

__global__ void k_final(const float* __restrict__ statz, const float* __restrict__ rhoW,
                        const float* __restrict__ rhob, float* __restrict__ out, int B){
  int b = blockIdx.x;
  int t = threadIdx.x; // 256
  if (t < 192){
    int i = t >> 6, d = t & 63;
    const float* z = statz + ((size_t)i*3 + 2)*(size_t)B*DH + (size_t)b*DH;
    float acc = rhob[i*RD + d];
    const float* Wm = rhoW + (size_t)i*DH*RD;
    for (int k = 0; k < DH; ++k) acc = fmaf(z[k], Wm[k*RD + d], acc);
    out[(size_t)b*640 + 64 + i*192 + d] = lrelu(lrelu(acc));
  }
  // lrelu the wmean sections: [0,64) U [128,256) U [320,448) U [512,640)
  for (int s = t; s < 448; s += 256){
    int idx;
    if (s < 64) idx = s;
    else { int j = s - 64; idx = 128 + (j >> 7)*192 + (j & 127); }
    size_t gi = (size_t)b*640 + idx;
    out[gi] = lrelu(out[gi]);
  }
}

// ---------------- launcher ----------------

extern "C" void kernel_launch(void* const* d_in, const int* in_sizes, int n_in,
                              void* d_out, int out_size, void* d_ws, size_t ws_size,
                              hipStream_t stream){
  const float* x    = (const float*)d_in[0];
  const float* ew   = (const float*)d_in[1];
  const float* gw   = (const float*)d_in[2];
  const float* W1   = (const float*)d_in[3];
  const float* W2   = (const float*)d_in[4];
  const float* W3   = (const float*)d_in[5];
  const float* sup  = (const float*)d_in[6];
  const float* AR   = (const float*)d_in[7];
  const float* gam  = (const float*)d_in[8];
  const float* bet  = (const float*)d_in[9];
  const float* alp  = (const float*)d_in[10];
  const float* phiW = (const float*)d_in[11];
  const float* phib = (const float*)d_in[12];
  const float* rhoW = (const float*)d_in[13];
  const float* rhob = (const float*)d_in[14];
  const int*   src  = (const int*)d_in[15];
  const int*   dst  = (const int*)d_in[16];
  float* out = (float*)d_out;

  int B = in_sizes[0] / (NN*FIN);
  size_t M = (size_t)B*NN;
  size_t BD = (size_t)B*DH;

  float* w = (float*)d_ws;
  size_t p = 0;
  float* nout = w+p; p += 1024;
  float* nin  = w+p; p += 1024;
  int* rp     = (int*)(w+p); p += 1024;
  int* ord    = (int*)(w+p); p += 1024;
  int* csr_s  = (int*)(w+p); p += 8192;
  int* csr_e  = (int*)(w+p); p += 8192;
  int* csr_d  = (int*)(w+p); p += 8192;
  float* statz = w+p; p += 3*3*BD;           // per layer: [ssum | ssq | zbuf]
  unsigned short* wt = (unsigned short*)(w+p); p += 45056;   // 90112 bf16
  int2* ecl   = (int2*)(w+p); p += (size_t)6*B*NE;
  unsigned short* hpre  = (unsigned short*)(w+p); p += M*DH/2;
  unsigned short* hnorm = (unsigned short*)(w+p); p += M*DH/2;
  unsigned short* agg   = (unsigned short*)(w+p); p += M*DH/2;

  hipMemsetAsync(out, 0, (size_t)out_size*sizeof(float), stream);

  k_prep<<<89 + B, 1024, 0, stream>>>(src, dst, W1, W2, W3, phiW, wt,
      x, gw, AR, out, nout, nin, rp, ord, csr_s, csr_e, csr_d, B);
  k_edge<<<12*B, 256, 0, stream>>>(ew, sup, nout, nin, csr_s, csr_e, csr_d,
      ecl, statz, (int)(9*BD/4), B);

  const int wt_off[3] = {0, 8192, 24576};

  for (int i = 0; i < 3; ++i){
    float* SS = statz + (size_t)i*3*BD;
    if (i == 0){
      k_gathF<<<B*63, 256, 0, stream>>>(x, ecl, rp, ord, agg, B);
      k_conv<FIN><<<B*16, 256, 0, stream>>>(agg, wt, hpre, SS, B);
    } else {
      k_gathB<<<B*63, 256, 0, stream>>>(hnorm, ecl + (size_t)i*B*NE, rp, ord, agg, B);
      k_conv<DH><<<B*16, 256, 0, stream>>>(agg, wt + wt_off[i], hpre, SS, B);
    }
    k_phi<<<B*16, 256, 0, stream>>>(hpre, wt + 40960 + i*16384,
        SS, SS + BD, alp + i*DH, gam + i*DH, bet + i*DH, phib + i*DH,
        gw, AR + (size_t)(i+1)*NN, (i == 2) ? nullptr : hnorm,
        SS + 2*BD, out, 128 + i*192, B);
  }

  k_final<<<B, 256, 0, stream>>>(statz, rhoW, rhob, out, B);
}